// Round 8
// baseline (241.914 us; speedup 1.0000x reference)
//
#include <hip/hip_runtime.h>

typedef __bf16 bf16;
typedef __attribute__((ext_vector_type(8))) __bf16 bf16x8;
typedef __attribute__((ext_vector_type(4))) __bf16 bf16x4;
typedef __attribute__((ext_vector_type(4))) float f32x4;

#define NB 4
#define NT 2048
#define ND 512
#define NH 8
#define NDK 64
#define GAMMA 0.1803368801111204f  // 0.125 * log2(e)
#define LTS 152                    // LT stride (shorts): 2-way-max bank alias

// workspace layout (bf16 elements)
#define OFF_XQ 0ull
#define OFF_XK 4194304ull
#define OFF_XV 8388608ull
#define OFF_XP 12582912ull
#define OFF_WQ 13631488ull
#define OFF_WK 13893632ull
#define OFF_WV 14155776ull
#define OFF_WP 14417920ull
#define OFF_WO 14680064ull
#define OFF_QU 14942208ull
#define OFF_QV 19136512ull
#define OFF_KB 23330816ull
#define OFF_VT 27525120ull
#define OFF_PB 31719424ull
#define OFF_OA OFF_XQ  // alias: Xq consumed by proj before flash writes Oa

// ---------------------------------------------------------------------------
// fp32 -> bf16 pre-convert of all GEMM operands (HBM-bound)
// ---------------------------------------------------------------------------
__global__ __launch_bounds__(256) void convert_bf16(
    const float* __restrict__ q, const float* __restrict__ k,
    const float* __restrict__ v, const float* __restrict__ p,
    const float* __restrict__ wq, const float* __restrict__ wk,
    const float* __restrict__ wv, const float* __restrict__ wp,
    const float* __restrict__ wo, bf16* __restrict__ dst) {
  int bid = blockIdx.x;
  const float* src;
  size_t doff;
  if (bid < 2048) { src = q; doff = OFF_XQ; }
  else if (bid < 4096) { src = k; doff = OFF_XK; bid -= 2048; }
  else if (bid < 6144) { src = v; doff = OFF_XV; bid -= 4096; }
  else if (bid < 6656) { src = p; doff = OFF_XP; bid -= 6144; }
  else if (bid < 6784) { src = wq; doff = OFF_WQ; bid -= 6656; }
  else if (bid < 6912) { src = wk; doff = OFF_WK; bid -= 6784; }
  else if (bid < 7040) { src = wv; doff = OFF_WV; bid -= 6912; }
  else if (bid < 7168) { src = wp; doff = OFF_WP; bid -= 7040; }
  else { src = wo; doff = OFF_WO; bid -= 7168; }
  size_t base = (size_t)bid * 2048 + threadIdx.x * 8;
  float4 x0 = *(const float4*)(src + base);
  float4 x1 = *(const float4*)(src + base + 4);
  bf16x8 o;
  o[0] = (bf16)x0.x; o[1] = (bf16)x0.y; o[2] = (bf16)x0.z; o[3] = (bf16)x0.w;
  o[4] = (bf16)x1.x; o[5] = (bf16)x1.y; o[6] = (bf16)x1.z; o[7] = (bf16)x1.w;
  *(bf16x8*)(dst + doff + base) = o;
}

// ---------------------------------------------------------------------------
// coalesced flush helper: LT is [128][LTS] flat LDS scratch of bf16 values
// ---------------------------------------------------------------------------
__device__ __forceinline__ void flush_tile(const bf16* LT, bf16* dst, int bm,
                                           int bn, int tid, bool isP) {
#pragma unroll
  for (int i = 0; i < 8; i++) {
    int chunk = tid + i * 256;
    int mm = chunk >> 4, c8 = (chunk & 15) * 8;
    bf16x8 vv = *(const bf16x8*)&LT[mm * LTS + c8];
    int n = bn + c8, h = n >> 6, d = n & 63;
    int gm = bm + mm;
    size_t gidx;
    if (isP)
      gidx = ((size_t)h * NT + gm) * NDK + d;
    else
      gidx = ((size_t)((gm >> 11) * NH + h) * NT + (gm & 2047)) * NDK + d;
    *(bf16x8*)(dst + gidx) = vv;
  }
}

// ---------------------------------------------------------------------------
// Fused projections (bf16 in, register-preload pipelined staging)
// mode 0: Qu/Qv (B,H,T,DK)  mode 1: K  mode 2: V transposed (B,H,DK,T)
// mode 3: P (H,T,DK)
// Modes 0/1/3 compute C^T (operand-swapped MFMA) so the epilogue packs 4
// n-consecutive values into one b64 LDS write (16/thread vs 64 scalar).
// ---------------------------------------------------------------------------
__global__ __launch_bounds__(256) void proj_fused(
    const bf16* __restrict__ Xq, const bf16* __restrict__ Xk,
    const bf16* __restrict__ Xv, const bf16* __restrict__ Xp,
    const bf16* __restrict__ wq, const bf16* __restrict__ wk,
    const bf16* __restrict__ wv, const bf16* __restrict__ wp,
    const float* __restrict__ bq, const float* __restrict__ bk,
    const float* __restrict__ bv, const float* __restrict__ pu,
    const float* __restrict__ pv, bf16* __restrict__ Qu, bf16* __restrict__ Qv,
    bf16* __restrict__ Kb, bf16* __restrict__ Vt, bf16* __restrict__ Pb) {
  __shared__ bf16 smem[2][128][76];  // staging; flat [128][152] for epilogue

  const int bid = blockIdx.x;
  const int mode = (bid >= 768) ? 3 : (bid >> 8);
  const int idx = (mode == 3) ? bid - 768 : (bid & 255);
  const int bm = (idx >> 2) * 128, bn = (idx & 3) * 128;

  const bf16* X;
  const bf16* W;
  if (mode == 0) { X = Xq; W = wq; }
  else if (mode == 1) { X = Xk; W = wk; }
  else if (mode == 2) { X = Xv; W = wv; }
  else { X = Xp; W = wp; }

  const int tid = threadIdx.x;
  const int l = tid & 63, w = tid >> 6;
  const int q = l >> 4, ln = l & 15;
  const int wm = (w >> 1) * 64, wn = (w & 1) * 64;

  f32x4 acc[4][4];
#pragma unroll
  for (int i = 0; i < 4; i++)
#pragma unroll
    for (int j = 0; j < 4; j++) acc[i][j] = (f32x4){0.f, 0.f, 0.f, 0.f};

  const int srow = tid >> 3, scol = (tid & 7) * 8;
  const size_t abase = (size_t)(bm + srow) * 512 + scol;
  const size_t bbase = (size_t)(bn + srow) * 512 + scol;

  bf16x8 ar[4], br[4];
#pragma unroll
  for (int i = 0; i < 4; i++) {
    ar[i] = *(const bf16x8*)(X + abase + (size_t)i * 32 * 512);
    br[i] = *(const bf16x8*)(W + bbase + (size_t)i * 32 * 512);
  }

  for (int k0 = 0; k0 < 512; k0 += 64) {
    __syncthreads();
#pragma unroll
    for (int i = 0; i < 4; i++) {
      *(bf16x8*)&smem[0][srow + i * 32][scol] = ar[i];
      *(bf16x8*)&smem[1][srow + i * 32][scol] = br[i];
    }
    if (k0 + 64 < 512) {
#pragma unroll
      for (int i = 0; i < 4; i++) {
        ar[i] = *(const bf16x8*)(X + abase + k0 + 64 + (size_t)i * 32 * 512);
        br[i] = *(const bf16x8*)(W + bbase + k0 + 64 + (size_t)i * 32 * 512);
      }
    }
    __syncthreads();
#pragma unroll
    for (int kc = 0; kc < 2; kc++) {
      bf16x8 af[4], bfr[4];
#pragma unroll
      for (int rt = 0; rt < 4; rt++)
        af[rt] = *(const bf16x8*)&smem[0][wm + rt * 16 + ln][kc * 32 + q * 8];
#pragma unroll
      for (int ct = 0; ct < 4; ct++)
        bfr[ct] = *(const bf16x8*)&smem[1][wn + ct * 16 + ln][kc * 32 + q * 8];
      if (mode == 2) {
#pragma unroll
        for (int rt = 0; rt < 4; rt++)
#pragma unroll
          for (int ct = 0; ct < 4; ct++)
            acc[rt][ct] = __builtin_amdgcn_mfma_f32_16x16x32_bf16(
                af[rt], bfr[ct], acc[rt][ct], 0, 0, 0);
      } else {  // swapped: acc = C^T tile (rows=n, cols=m)
#pragma unroll
        for (int rt = 0; rt < 4; rt++)
#pragma unroll
          for (int ct = 0; ct < 4; ct++)
            acc[rt][ct] = __builtin_amdgcn_mfma_f32_16x16x32_bf16(
                bfr[ct], af[rt], acc[rt][ct], 0, 0, 0);
      }
    }
  }

  bf16* LT = &smem[0][0][0];  // flat [128][LTS] scratch

  if (mode == 2) {
    __syncthreads();
#pragma unroll
    for (int ct = 0; ct < 4; ct++) {
      const int n = bn + wn + ct * 16 + ln;
      const float bvn = bv[n];
#pragma unroll
      for (int rt = 0; rt < 4; rt++) {
        bf16x4 t4;
#pragma unroll
        for (int r = 0; r < 4; r++) t4[r] = (bf16)(acc[rt][ct][r] + bvn);
        *(bf16x4*)&LT[(wn + ct * 16 + ln) * LTS + wm + rt * 16 + q * 4] = t4;
      }
    }
    __syncthreads();
    const int b = bm >> 11, tb = bm & 2047;
#pragma unroll
    for (int i = 0; i < 8; i++) {
      int chunk = tid + i * 256;
      int nn = chunk >> 4, m8 = (chunk & 15) * 8;
      int n = bn + nn, h = n >> 6, d = n & 63;
      size_t gidx = (((size_t)(b * NH + h)) * NDK + d) * NT + tb + m8;
      *(bf16x8*)(Vt + gidx) = *(const bf16x8*)&LT[nn * LTS + m8];
    }
    return;
  }

  // modes 0/1/3: acc is C^T; lane holds 4 n-consecutive values per tile.
  const int mloc = wm + ln;          // + rt*16
  const int nloc = wn + q * 4;       // + ct*16 (n0 of this lane's 4 values)

  if (mode == 0) {
    float4 addu4[4], addv4[4];
#pragma unroll
    for (int ct = 0; ct < 4; ct++) {
      int n0 = bn + nloc + ct * 16;
      float4 bb = *(const float4*)(bq + n0);
      float4 uu = *(const float4*)(pu + n0);
      float4 vv = *(const float4*)(pv + n0);
      addu4[ct] = make_float4(bb.x + uu.x, bb.y + uu.y, bb.z + uu.z, bb.w + uu.w);
      addv4[ct] = make_float4(bb.x + vv.x, bb.y + vv.y, bb.z + vv.z, bb.w + vv.w);
    }
    __syncthreads();
#pragma unroll
    for (int rt = 0; rt < 4; rt++)
#pragma unroll
      for (int ct = 0; ct < 4; ct++) {
        const float* au = &addu4[ct].x;
        bf16x4 t4;
#pragma unroll
        for (int r = 0; r < 4; r++)
          t4[r] = (bf16)((acc[rt][ct][r] + au[r]) * GAMMA);
        *(bf16x4*)&LT[(mloc + rt * 16) * LTS + nloc + ct * 16] = t4;
      }
    __syncthreads();
    flush_tile(LT, Qu, bm, bn, tid, false);
    __syncthreads();
#pragma unroll
    for (int rt = 0; rt < 4; rt++)
#pragma unroll
      for (int ct = 0; ct < 4; ct++) {
        const float* av = &addv4[ct].x;
        bf16x4 t4;
#pragma unroll
        for (int r = 0; r < 4; r++)
          t4[r] = (bf16)((acc[rt][ct][r] + av[r]) * GAMMA);
        *(bf16x4*)&LT[(mloc + rt * 16) * LTS + nloc + ct * 16] = t4;
      }
    __syncthreads();
    flush_tile(LT, Qv, bm, bn, tid, false);
    return;
  }

  // mode 1 (K) and mode 3 (P)
  {
    float4 bb4[4];
#pragma unroll
    for (int ct = 0; ct < 4; ct++) {
      int n0 = bn + nloc + ct * 16;
      bb4[ct] = (mode == 1) ? *(const float4*)(bk + n0)
                            : make_float4(0.f, 0.f, 0.f, 0.f);
    }
    __syncthreads();
#pragma unroll
    for (int rt = 0; rt < 4; rt++)
#pragma unroll
      for (int ct = 0; ct < 4; ct++) {
        const float* bbp = &bb4[ct].x;
        bf16x4 t4;
#pragma unroll
        for (int r = 0; r < 4; r++) t4[r] = (bf16)(acc[rt][ct][r] + bbp[r]);
        *(bf16x4*)&LT[(mloc + rt * 16) * LTS + nloc + ct * 16] = t4;
      }
    __syncthreads();
    flush_tile(LT, (mode == 1) ? Kb : Pb, bm, bn, tid, mode == 3);
  }
}

// ---------------------------------------------------------------------------
// Flash attention: 1024 threads = 16 waves x 16 q-rows = 256-row Q-tile.
// Grid (32 bh, 8 t): bh on fast dim -> all blocks of a head land on one XCD
// (per-XCD working set 2.25 MB < 4 MiB L2, proven 82->17.6 MB FETCH in R7).
// 16 waves/CU = 4 waves/SIMD: latency hiding the 8-wave version lacked.
// S^T via operand-swapped MFMA; per-wave sPT C->A roundtrip; no-max softmax.
// ---------------------------------------------------------------------------
__global__ __launch_bounds__(1024) void flash(
    const bf16* __restrict__ Qu, const bf16* __restrict__ Qv,
    const bf16* __restrict__ Kb, const bf16* __restrict__ Pb,
    const bf16* __restrict__ Vt, const int* __restrict__ mask,
    bf16* __restrict__ Oa) {
  __shared__ bf16 sK[64][136];      // [s][0:64]=K, [64:128]=P
  __shared__ bf16 sVt[64][72];      // [d][s]
  __shared__ bf16 sPT[16][16][40];  // per-wave P^T: [t][s_half32], +8 pad
  __shared__ float sbias[64];

  const int tid = threadIdx.x;
  const int l = tid & 63, wv = tid >> 6;  // 16 waves
  const int q = l >> 4, ln = l & 15;
  const int bh = blockIdx.x;  // fast dim -> XCD = bh % 8 = h (L2 locality)
  const int t0 = blockIdx.y * 256;
  const int b = bh >> 3;

  // Q fragments: one 16-row t-tile per wave, resident all kernel
  const size_t qrow = (((size_t)bh) * NT + t0 + wv * 16 + ln) * NDK;
  bf16x8 qf[4];
  qf[0] = *(const bf16x8*)(Qu + qrow + q * 8);
  qf[1] = *(const bf16x8*)(Qu + qrow + 32 + q * 8);
  qf[2] = *(const bf16x8*)(Qv + qrow + q * 8);
  qf[3] = *(const bf16x8*)(Qv + qrow + 32 + q * 8);

  int okacc = 1;
  for (int i = tid; i < NT; i += 1024) okacc &= (mask[b * NT + i] != 0);
  const int allones = __syncthreads_and(okacc);

  float lsum = 0.f;
  f32x4 O[4];
#pragma unroll
  for (int dt = 0; dt < 4; dt++) O[dt] = (f32x4){0.f, 0.f, 0.f, 0.f};

  const bf16* Krow = Kb + ((size_t)bh) * NT * NDK;
  const bf16* Prow = Pb + ((size_t)(bh & 7)) * NT * NDK;
  const bf16* Vrow = Vt + ((size_t)bh) * NDK * NT;

  // staging geometry (1024 threads: 1 K|P chunk each; half stage V)
  const int krow = tid >> 4, kcc = tid & 15;
  const int vrow = (tid & 511) >> 3, vcol = (tid & 7) * 8;
  const bool doV = (tid < 512);
  const bf16* kpsrc = (kcc < 8) ? (Krow + kcc * 8) : (Prow + (kcc - 8) * 8);

  bf16x8 rk, rv;
  rk = *(const bf16x8*)(kpsrc + (size_t)krow * NDK);
  if (doV) rv = *(const bf16x8*)(Vrow + (size_t)vrow * NT + vcol);

  for (int s0 = 0; s0 < NT; s0 += 64) {
    __syncthreads();  // previous tile's reads complete
    *(bf16x8*)&sK[krow][kcc * 8] = rk;
    if (doV) *(bf16x8*)&sVt[vrow][vcol] = rv;
    if (s0 + 64 < NT) {
      rk = *(const bf16x8*)(kpsrc + (size_t)(s0 + 64 + krow) * NDK);
      if (doV)
        rv = *(const bf16x8*)(Vrow + (size_t)vrow * NT + s0 + 64 + vcol);
    }
    if (!allones && tid < 64)
      sbias[tid] = mask[b * NT + s0 + tid] ? 0.f : -1e30f;
    __syncthreads();  // writes visible

    // S^T tiles: mfma(A=K-frag, B=Q-frag) -> D[s][t]
    f32x4 ST[4];
#pragma unroll
    for (int ct = 0; ct < 4; ct++) {
      ST[ct] = (f32x4){0.f, 0.f, 0.f, 0.f};
#pragma unroll
      for (int kc = 0; kc < 4; kc++) {
        bf16x8 kf = *(const bf16x8*)&sK[ct * 16 + ln][kc * 32 + q * 8];
        ST[ct] = __builtin_amdgcn_mfma_f32_16x16x32_bf16(kf, qf[kc], ST[ct], 0,
                                                         0, 0);
      }
    }
    if (!allones) {
#pragma unroll
      for (int ct = 0; ct < 4; ct++) {
        float4 bb = *(const float4*)&sbias[ct * 16 + q * 4];
        ST[ct][0] += bb.x;
        ST[ct][1] += bb.y;
        ST[ct][2] += bb.z;
        ST[ct][3] += bb.w;
      }
    }
    // exp2 + truncate-pack + PV, per 32-s half
#pragma unroll
    for (int c = 0; c < 2; c++) {
#pragma unroll
      for (int cc = 0; cc < 2; cc++) {
        const int ct = c * 2 + cc;
        unsigned u0 =
            __builtin_bit_cast(unsigned, __builtin_amdgcn_exp2f(ST[ct][0]));
        unsigned u1 =
            __builtin_bit_cast(unsigned, __builtin_amdgcn_exp2f(ST[ct][1]));
        unsigned u2 =
            __builtin_bit_cast(unsigned, __builtin_amdgcn_exp2f(ST[ct][2]));
        unsigned u3 =
            __builtin_bit_cast(unsigned, __builtin_amdgcn_exp2f(ST[ct][3]));
        // truncated bf16 used for BOTH numerator (P@V) and denominator
        lsum += __builtin_bit_cast(float, u0 & 0xffff0000u) +
                __builtin_bit_cast(float, u1 & 0xffff0000u) +
                __builtin_bit_cast(float, u2 & 0xffff0000u) +
                __builtin_bit_cast(float, u3 & 0xffff0000u);
        uint2 pk;
        pk.x = (u0 >> 16) | (u1 & 0xffff0000u);
        pk.y = (u2 >> 16) | (u3 & 0xffff0000u);
        *(uint2*)&sPT[wv][ln][cc * 16 + q * 4] = pk;
      }
      bf16x8 paf = *(const bf16x8*)&sPT[wv][ln][q * 8];
#pragma unroll
      for (int dt = 0; dt < 4; dt++) {
        bf16x8 vb = *(const bf16x8*)&sVt[dt * 16 + ln][c * 32 + q * 8];
        O[dt] =
            __builtin_amdgcn_mfma_f32_16x16x32_bf16(paf, vb, O[dt], 0, 0, 0);
      }
    }
  }

  // epilogue: reduce lsum across quads; write O as (B,T,H*DK)
  float s = lsum;
  s += __shfl_xor(s, 16);
  s += __shfl_xor(s, 32);
#pragma unroll
  for (int r = 0; r < 4; r++) {
    float dr = __shfl(s, q * 4 + r);  // lane q*4+r holds denom for that row
    float inv = (dr > 0.f) ? 1.f / dr : 0.f;
    int t = t0 + wv * 16 + q * 4 + r;
    size_t base = (((size_t)b * NT + t) * NH + (bh & 7)) * NDK;
#pragma unroll
    for (int dt = 0; dt < 4; dt++)
      Oa[base + dt * 16 + ln] = (bf16)(O[dt][r] * inv);
  }
}

// ---------------------------------------------------------------------------
// Output GEMM: 128x64 tiles, bf16 A and W (pre-converted), fp32 out
// ---------------------------------------------------------------------------
__global__ __launch_bounds__(256) void out_gemm(const bf16* __restrict__ A,
                                                const bf16* __restrict__ W,
                                                const float* __restrict__ bias,
                                                float* __restrict__ out) {
  __shared__ bf16 sA[128][72];
  __shared__ bf16 sB[64][72];

  const int tid = threadIdx.x;
  const int l = tid & 63, w = tid >> 6;
  const int q = l >> 4, ln = l & 15;
  const int wm = (w >> 1) * 64, wn = (w & 1) * 32;
  const int bm = blockIdx.x * 128, bn = blockIdx.y * 64;

  f32x4 acc[4][2];
#pragma unroll
  for (int i = 0; i < 4; i++)
#pragma unroll
    for (int j = 0; j < 2; j++) acc[i][j] = (f32x4){0.f, 0.f, 0.f, 0.f};

  const int srow = tid >> 3, scol = (tid & 7) * 8;
  const size_t abase = (size_t)(bm + srow) * 512 + scol;
  const size_t bbase = (size_t)(bn + srow) * 512 + scol;

  bf16x8 ar[4], br[2];
#pragma unroll
  for (int i = 0; i < 4; i++)
    ar[i] = *(const bf16x8*)(A + abase + (size_t)i * 32 * 512);
#pragma unroll
  for (int i = 0; i < 2; i++)
    br[i] = *(const bf16x8*)(W + bbase + (size_t)i * 32 * 512);

  for (int k0 = 0; k0 < 512; k0 += 64) {
    __syncthreads();
#pragma unroll
    for (int i = 0; i < 4; i++) *(bf16x8*)&sA[srow + i * 32][scol] = ar[i];
#pragma unroll
    for (int i = 0; i < 2; i++) *(bf16x8*)&sB[srow + i * 32][scol] = br[i];
    if (k0 + 64 < 512) {
#pragma unroll
      for (int i = 0; i < 4; i++)
        ar[i] = *(const bf16x8*)(A + abase + k0 + 64 + (size_t)i * 32 * 512);
#pragma unroll
      for (int i = 0; i < 2; i++)
        br[i] = *(const bf16x8*)(W + bbase + k0 + 64 + (size_t)i * 32 * 512);
    }
    __syncthreads();
#pragma unroll
    for (int kc = 0; kc < 2; kc++) {
      bf16x8 af[4], bfr[2];
#pragma unroll
      for (int rt = 0; rt < 4; rt++)
        af[rt] = *(const bf16x8*)&sA[wm + rt * 16 + ln][kc * 32 + q * 8];
#pragma unroll
      for (int ct = 0; ct < 2; ct++)
        bfr[ct] = *(const bf16x8*)&sB[wn + ct * 16 + ln][kc * 32 + q * 8];
#pragma unroll
      for (int rt = 0; rt < 4; rt++)
#pragma unroll
        for (int ct = 0; ct < 2; ct++)
          acc[rt][ct] = __builtin_amdgcn_mfma_f32_16x16x32_bf16(
              af[rt], bfr[ct], acc[rt][ct], 0, 0, 0);
    }
  }

#pragma unroll
  for (int rt = 0; rt < 4; rt++)
#pragma unroll
    for (int ct = 0; ct < 2; ct++) {
      const int n = bn + wn + ct * 16 + ln;
      const float bias_n = bias[n];
#pragma unroll
      for (int r = 0; r < 4; r++) {
        const int m = bm + wm + rt * 16 + q * 4 + r;
        out[(size_t)m * 512 + n] = acc[rt][ct][r] + bias_n;
      }
    }
}

// ---------------------------------------------------------------------------
extern "C" void kernel_launch(void* const* d_in, const int* in_sizes, int n_in,
                              void* d_out, int out_size, void* d_ws,
                              size_t ws_size, hipStream_t stream) {
  const float* query = (const float*)d_in[0];
  const float* key = (const float*)d_in[1];
  const float* value = (const float*)d_in[2];
  const int* mask = (const int*)d_in[3];
  const float* pos = (const float*)d_in[4];
  const float* Wq = (const float*)d_in[5];
  const float* bq = (const float*)d_in[6];
  const float* Wk = (const float*)d_in[7];
  const float* bk = (const float*)d_in[8];
  const float* Wv = (const float*)d_in[9];
  const float* bv = (const float*)d_in[10];
  const float* Wo = (const float*)d_in[11];
  const float* bo = (const float*)d_in[12];
  const float* Wp = (const float*)d_in[13];
  const float* pu = (const float*)d_in[14];
  const float* pv = (const float*)d_in[15];
  float* out = (float*)d_out;

  bf16* ws = (bf16*)d_ws;
  dim3 blk(256);
  convert_bf16<<<dim3(7296), blk, 0, stream>>>(query, key, value, pos, Wq, Wk,
                                               Wv, Wp, Wo, ws);
  proj_fused<<<dim3(832), blk, 0, stream>>>(
      ws + OFF_XQ, ws + OFF_XK, ws + OFF_XV, ws + OFF_XP, ws + OFF_WQ,
      ws + OFF_WK, ws + OFF_WV, ws + OFF_WP, bq, bk, bv, pu, pv, ws + OFF_QU,
      ws + OFF_QV, ws + OFF_KB, ws + OFF_VT, ws + OFF_PB);
  flash<<<dim3(32, 8), dim3(1024), 0, stream>>>(ws + OFF_QU, ws + OFF_QV,
                                                ws + OFF_KB, ws + OFF_PB,
                                                ws + OFF_VT, mask, ws + OFF_OA);
  out_gemm<<<dim3(64, 8), blk, 0, stream>>>(ws + OFF_OA, ws + OFF_WO, bo, out);
}

// Round 9
// 223.939 us; speedup vs baseline: 1.0803x; 1.0803x over previous
//
#include <hip/hip_runtime.h>

typedef __bf16 bf16;
typedef __attribute__((ext_vector_type(8))) __bf16 bf16x8;
typedef __attribute__((ext_vector_type(4))) __bf16 bf16x4;
typedef __attribute__((ext_vector_type(4))) float f32x4;
typedef __attribute__((ext_vector_type(4))) short s4;

#define NB 4
#define NT 2048
#define ND 512
#define NH 8
#define NDK 64
#define GAMMA 0.1803368801111204f  // 0.125 * log2(e)
#define LTS 152                    // LT stride (shorts)

// workspace layout (bf16 elements)
#define OFF_XQ 0ull
#define OFF_XK 4194304ull
#define OFF_XV 8388608ull
#define OFF_XP 12582912ull
#define OFF_WQ 13631488ull
#define OFF_WK 13893632ull
#define OFF_WV 14155776ull
#define OFF_WP 14417920ull
#define OFF_WO 14680064ull
#define OFF_QU 14942208ull
#define OFF_QV 19136512ull
#define OFF_KB 23330816ull
#define OFF_VT 27525120ull
#define OFF_PB 31719424ull
#define OFF_OA OFF_XQ  // alias: Xq consumed by proj before flash writes Oa

// K=16 bf16 MFMA: A-frag layout == our S^T C/D layout -> direct feed, no LDS
static __device__ __forceinline__ f32x4 mfma16b(s4 a, s4 b, f32x4 c) {
#if __has_builtin(__builtin_amdgcn_mfma_f32_16x16x16bf16_1k)
  return __builtin_amdgcn_mfma_f32_16x16x16bf16_1k(a, b, c, 0, 0, 0);
#else
  f32x4 d;
  asm("v_mfma_f32_16x16x16_bf16 %0, %1, %2, %3"
      : "=v"(d)
      : "v"(a), "v"(b), "v"(c));
  return d;
#endif
}

// ---------------------------------------------------------------------------
// fp32 -> bf16 pre-convert of all GEMM operands (HBM-bound)
// ---------------------------------------------------------------------------
__global__ __launch_bounds__(256) void convert_bf16(
    const float* __restrict__ q, const float* __restrict__ k,
    const float* __restrict__ v, const float* __restrict__ p,
    const float* __restrict__ wq, const float* __restrict__ wk,
    const float* __restrict__ wv, const float* __restrict__ wp,
    const float* __restrict__ wo, bf16* __restrict__ dst) {
  int bid = blockIdx.x;
  const float* src;
  size_t doff;
  if (bid < 2048) { src = q; doff = OFF_XQ; }
  else if (bid < 4096) { src = k; doff = OFF_XK; bid -= 2048; }
  else if (bid < 6144) { src = v; doff = OFF_XV; bid -= 4096; }
  else if (bid < 6656) { src = p; doff = OFF_XP; bid -= 6144; }
  else if (bid < 6784) { src = wq; doff = OFF_WQ; bid -= 6656; }
  else if (bid < 6912) { src = wk; doff = OFF_WK; bid -= 6784; }
  else if (bid < 7040) { src = wv; doff = OFF_WV; bid -= 6912; }
  else if (bid < 7168) { src = wp; doff = OFF_WP; bid -= 7040; }
  else { src = wo; doff = OFF_WO; bid -= 7168; }
  size_t base = (size_t)bid * 2048 + threadIdx.x * 8;
  float4 x0 = *(const float4*)(src + base);
  float4 x1 = *(const float4*)(src + base + 4);
  bf16x8 o;
  o[0] = (bf16)x0.x; o[1] = (bf16)x0.y; o[2] = (bf16)x0.z; o[3] = (bf16)x0.w;
  o[4] = (bf16)x1.x; o[5] = (bf16)x1.y; o[6] = (bf16)x1.z; o[7] = (bf16)x1.w;
  *(bf16x8*)(dst + doff + base) = o;
}

// ---------------------------------------------------------------------------
// coalesced flush helper: LT is [128][LTS] flat LDS scratch of bf16 values
// ---------------------------------------------------------------------------
__device__ __forceinline__ void flush_tile(const bf16* LT, bf16* dst, int bm,
                                           int bn, int tid, bool isP) {
#pragma unroll
  for (int i = 0; i < 8; i++) {
    int chunk = tid + i * 256;
    int mm = chunk >> 4, c8 = (chunk & 15) * 8;
    bf16x8 vv = *(const bf16x8*)&LT[mm * LTS + c8];
    int n = bn + c8, h = n >> 6, d = n & 63;
    int gm = bm + mm;
    size_t gidx;
    if (isP)
      gidx = ((size_t)h * NT + gm) * NDK + d;
    else
      gidx = ((size_t)((gm >> 11) * NH + h) * NT + (gm & 2047)) * NDK + d;
    *(bf16x8*)(dst + gidx) = vv;
  }
}

// ---------------------------------------------------------------------------
// Fused projections (bf16 in, register-preload pipelined staging)
// mode 0: Qu/Qv (B,H,T,DK)  mode 1: K  mode 2: V transposed (B,H,DK,T)
// mode 3: P (H,T,DK).  Modes 0/1/3 compute C^T (swapped MFMA) -> b64 writes.
// ---------------------------------------------------------------------------
__global__ __launch_bounds__(256) void proj_fused(
    const bf16* __restrict__ Xq, const bf16* __restrict__ Xk,
    const bf16* __restrict__ Xv, const bf16* __restrict__ Xp,
    const bf16* __restrict__ wq, const bf16* __restrict__ wk,
    const bf16* __restrict__ wv, const bf16* __restrict__ wp,
    const float* __restrict__ bq, const float* __restrict__ bk,
    const float* __restrict__ bv, const float* __restrict__ pu,
    const float* __restrict__ pv, bf16* __restrict__ Qu, bf16* __restrict__ Qv,
    bf16* __restrict__ Kb, bf16* __restrict__ Vt, bf16* __restrict__ Pb) {
  __shared__ bf16 smem[2][128][76];  // staging; flat [128][152] for epilogue

  const int bid = blockIdx.x;
  const int mode = (bid >= 768) ? 3 : (bid >> 8);
  const int idx = (mode == 3) ? bid - 768 : (bid & 255);
  const int bm = (idx >> 2) * 128, bn = (idx & 3) * 128;

  const bf16* X;
  const bf16* W;
  if (mode == 0) { X = Xq; W = wq; }
  else if (mode == 1) { X = Xk; W = wk; }
  else if (mode == 2) { X = Xv; W = wv; }
  else { X = Xp; W = wp; }

  const int tid = threadIdx.x;
  const int l = tid & 63, w = tid >> 6;
  const int q = l >> 4, ln = l & 15;
  const int wm = (w >> 1) * 64, wn = (w & 1) * 64;

  f32x4 acc[4][4];
#pragma unroll
  for (int i = 0; i < 4; i++)
#pragma unroll
    for (int j = 0; j < 4; j++) acc[i][j] = (f32x4){0.f, 0.f, 0.f, 0.f};

  const int srow = tid >> 3, scol = (tid & 7) * 8;
  const size_t abase = (size_t)(bm + srow) * 512 + scol;
  const size_t bbase = (size_t)(bn + srow) * 512 + scol;

  bf16x8 ar[4], br[4];
#pragma unroll
  for (int i = 0; i < 4; i++) {
    ar[i] = *(const bf16x8*)(X + abase + (size_t)i * 32 * 512);
    br[i] = *(const bf16x8*)(W + bbase + (size_t)i * 32 * 512);
  }

  for (int k0 = 0; k0 < 512; k0 += 64) {
    __syncthreads();
#pragma unroll
    for (int i = 0; i < 4; i++) {
      *(bf16x8*)&smem[0][srow + i * 32][scol] = ar[i];
      *(bf16x8*)&smem[1][srow + i * 32][scol] = br[i];
    }
    if (k0 + 64 < 512) {
#pragma unroll
      for (int i = 0; i < 4; i++) {
        ar[i] = *(const bf16x8*)(X + abase + k0 + 64 + (size_t)i * 32 * 512);
        br[i] = *(const bf16x8*)(W + bbase + k0 + 64 + (size_t)i * 32 * 512);
      }
    }
    __syncthreads();
#pragma unroll
    for (int kc = 0; kc < 2; kc++) {
      bf16x8 af[4], bfr[4];
#pragma unroll
      for (int rt = 0; rt < 4; rt++)
        af[rt] = *(const bf16x8*)&smem[0][wm + rt * 16 + ln][kc * 32 + q * 8];
#pragma unroll
      for (int ct = 0; ct < 4; ct++)
        bfr[ct] = *(const bf16x8*)&smem[1][wn + ct * 16 + ln][kc * 32 + q * 8];
      if (mode == 2) {
#pragma unroll
        for (int rt = 0; rt < 4; rt++)
#pragma unroll
          for (int ct = 0; ct < 4; ct++)
            acc[rt][ct] = __builtin_amdgcn_mfma_f32_16x16x32_bf16(
                af[rt], bfr[ct], acc[rt][ct], 0, 0, 0);
      } else {  // swapped: acc = C^T tile (rows=n, cols=m)
#pragma unroll
        for (int rt = 0; rt < 4; rt++)
#pragma unroll
          for (int ct = 0; ct < 4; ct++)
            acc[rt][ct] = __builtin_amdgcn_mfma_f32_16x16x32_bf16(
                bfr[ct], af[rt], acc[rt][ct], 0, 0, 0);
      }
    }
  }

  bf16* LT = &smem[0][0][0];  // flat [128][LTS] scratch

  if (mode == 2) {
    __syncthreads();
#pragma unroll
    for (int ct = 0; ct < 4; ct++) {
      const int n = bn + wn + ct * 16 + ln;
      const float bvn = bv[n];
#pragma unroll
      for (int rt = 0; rt < 4; rt++) {
        bf16x4 t4;
#pragma unroll
        for (int r = 0; r < 4; r++) t4[r] = (bf16)(acc[rt][ct][r] + bvn);
        *(bf16x4*)&LT[(wn + ct * 16 + ln) * LTS + wm + rt * 16 + q * 4] = t4;
      }
    }
    __syncthreads();
    const int b = bm >> 11, tb = bm & 2047;
#pragma unroll
    for (int i = 0; i < 8; i++) {
      int chunk = tid + i * 256;
      int nn = chunk >> 4, m8 = (chunk & 15) * 8;
      int n = bn + nn, h = n >> 6, d = n & 63;
      size_t gidx = (((size_t)(b * NH + h)) * NDK + d) * NT + tb + m8;
      *(bf16x8*)(Vt + gidx) = *(const bf16x8*)&LT[nn * LTS + m8];
    }
    return;
  }

  // modes 0/1/3: acc is C^T; lane holds 4 n-consecutive values per tile.
  const int mloc = wm + ln;     // + rt*16
  const int nloc = wn + q * 4;  // + ct*16

  if (mode == 0) {
    float4 addu4[4], addv4[4];
#pragma unroll
    for (int ct = 0; ct < 4; ct++) {
      int n0 = bn + nloc + ct * 16;
      float4 bb = *(const float4*)(bq + n0);
      float4 uu = *(const float4*)(pu + n0);
      float4 vv = *(const float4*)(pv + n0);
      addu4[ct] = make_float4(bb.x + uu.x, bb.y + uu.y, bb.z + uu.z, bb.w + uu.w);
      addv4[ct] = make_float4(bb.x + vv.x, bb.y + vv.y, bb.z + vv.z, bb.w + vv.w);
    }
    __syncthreads();
#pragma unroll
    for (int rt = 0; rt < 4; rt++)
#pragma unroll
      for (int ct = 0; ct < 4; ct++) {
        const float* au = &addu4[ct].x;
        bf16x4 t4;
#pragma unroll
        for (int r = 0; r < 4; r++)
          t4[r] = (bf16)((acc[rt][ct][r] + au[r]) * GAMMA);
        *(bf16x4*)&LT[(mloc + rt * 16) * LTS + nloc + ct * 16] = t4;
      }
    __syncthreads();
    flush_tile(LT, Qu, bm, bn, tid, false);
    __syncthreads();
#pragma unroll
    for (int rt = 0; rt < 4; rt++)
#pragma unroll
      for (int ct = 0; ct < 4; ct++) {
        const float* av = &addv4[ct].x;
        bf16x4 t4;
#pragma unroll
        for (int r = 0; r < 4; r++)
          t4[r] = (bf16)((acc[rt][ct][r] + av[r]) * GAMMA);
        *(bf16x4*)&LT[(mloc + rt * 16) * LTS + nloc + ct * 16] = t4;
      }
    __syncthreads();
    flush_tile(LT, Qv, bm, bn, tid, false);
    return;
  }

  // mode 1 (K) and mode 3 (P)
  {
    float4 bb4[4];
#pragma unroll
    for (int ct = 0; ct < 4; ct++) {
      int n0 = bn + nloc + ct * 16;
      bb4[ct] = (mode == 1) ? *(const float4*)(bk + n0)
                            : make_float4(0.f, 0.f, 0.f, 0.f);
    }
    __syncthreads();
#pragma unroll
    for (int rt = 0; rt < 4; rt++)
#pragma unroll
      for (int ct = 0; ct < 4; ct++) {
        const float* bbp = &bb4[ct].x;
        bf16x4 t4;
#pragma unroll
        for (int r = 0; r < 4; r++) t4[r] = (bf16)(acc[rt][ct][r] + bbp[r]);
        *(bf16x4*)&LT[(mloc + rt * 16) * LTS + nloc + ct * 16] = t4;
      }
    __syncthreads();
    flush_tile(LT, (mode == 1) ? Kb : Pb, bm, bn, tid, mode == 3);
  }
}

// ---------------------------------------------------------------------------
// Flash attention, R5 shape: 512 thr = 8 waves x 32 q-rows (dual 16-row
// tiles), grid (8 t, 32 bh). NEW: PV uses K=16 MFMA whose A-operand layout
// equals S^T's C/D layout -> exp2 results feed MFMA directly from registers.
// No P LDS round-trip at all. No-max softmax in log2 domain.
// ---------------------------------------------------------------------------
__global__ __launch_bounds__(512) void flash(
    const bf16* __restrict__ Qu, const bf16* __restrict__ Qv,
    const bf16* __restrict__ Kb, const bf16* __restrict__ Pb,
    const bf16* __restrict__ Vt, const int* __restrict__ mask,
    bf16* __restrict__ Oa) {
  __shared__ bf16 sK[64][136];  // [s][0:64]=K, [64:128]=P
  __shared__ bf16 sVt[64][72];  // [d][s]
  __shared__ float sbias[64];

  const int tid = threadIdx.x;
  const int l = tid & 63, wv = tid >> 6;  // 8 waves
  const int q = l >> 4, ln = l & 15;
  const int t0 = blockIdx.x * 256;
  const int bh = blockIdx.y;
  const int b = bh >> 3;

  // Q fragments: 2 t-tiles of 16 rows per wave, resident all kernel
  bf16x8 qf[2][4];
#pragma unroll
  for (int tt = 0; tt < 2; tt++) {
    const size_t qrow = (((size_t)bh) * NT + t0 + wv * 32 + tt * 16 + ln) * NDK;
    qf[tt][0] = *(const bf16x8*)(Qu + qrow + q * 8);
    qf[tt][1] = *(const bf16x8*)(Qu + qrow + 32 + q * 8);
    qf[tt][2] = *(const bf16x8*)(Qv + qrow + q * 8);
    qf[tt][3] = *(const bf16x8*)(Qv + qrow + 32 + q * 8);
  }

  int okacc = 1;
  for (int i = tid; i < NT; i += 512) okacc &= (mask[b * NT + i] != 0);
  const int allones = __syncthreads_and(okacc);

  float lsum[2] = {0.f, 0.f};
  f32x4 O[2][4];
#pragma unroll
  for (int tt = 0; tt < 2; tt++)
#pragma unroll
    for (int dt = 0; dt < 4; dt++) O[tt][dt] = (f32x4){0.f, 0.f, 0.f, 0.f};

  const bf16* Krow = Kb + ((size_t)bh) * NT * NDK;
  const bf16* Prow = Pb + ((size_t)(bh & 7)) * NT * NDK;
  const bf16* Vrow = Vt + ((size_t)bh) * NDK * NT;

  // staging geometry (512 threads)
  const int krow = tid >> 4, kcc = tid & 15;        // K|P: rows krow + i*32
  const int vrow = tid >> 3, vcol = (tid & 7) * 8;  // V: 1 chunk/thread
  const bf16* kpsrc = (kcc < 8) ? (Krow + kcc * 8) : (Prow + (kcc - 8) * 8);

  bf16x8 rk[2], rv;
#pragma unroll
  for (int i = 0; i < 2; i++)
    rk[i] = *(const bf16x8*)(kpsrc + (size_t)(krow + i * 32) * NDK);
  rv = *(const bf16x8*)(Vrow + (size_t)vrow * NT + vcol);

  for (int s0 = 0; s0 < NT; s0 += 64) {
    __syncthreads();  // previous tile's reads complete
#pragma unroll
    for (int i = 0; i < 2; i++) *(bf16x8*)&sK[krow + i * 32][kcc * 8] = rk[i];
    *(bf16x8*)&sVt[vrow][vcol] = rv;
    if (s0 + 64 < NT) {
#pragma unroll
      for (int i = 0; i < 2; i++)
        rk[i] =
            *(const bf16x8*)(kpsrc + (size_t)(s0 + 64 + krow + i * 32) * NDK);
      rv = *(const bf16x8*)(Vrow + (size_t)vrow * NT + s0 + 64 + vcol);
    }
    if (!allones && tid < 64)
      sbias[tid] = mask[b * NT + s0 + tid] ? 0.f : -1e30f;
    __syncthreads();  // writes visible

    // S^T tiles: mfma(A=K-frag, B=Q-frag) -> D[s][t], both t-tiles share kf
    f32x4 ST[2][4];
#pragma unroll
    for (int ct = 0; ct < 4; ct++) {
      ST[0][ct] = (f32x4){0.f, 0.f, 0.f, 0.f};
      ST[1][ct] = (f32x4){0.f, 0.f, 0.f, 0.f};
#pragma unroll
      for (int kc = 0; kc < 4; kc++) {
        bf16x8 kf = *(const bf16x8*)&sK[ct * 16 + ln][kc * 32 + q * 8];
        ST[0][ct] = __builtin_amdgcn_mfma_f32_16x16x32_bf16(kf, qf[0][kc],
                                                            ST[0][ct], 0, 0, 0);
        ST[1][ct] = __builtin_amdgcn_mfma_f32_16x16x32_bf16(kf, qf[1][kc],
                                                            ST[1][ct], 0, 0, 0);
      }
    }
    if (!allones) {
#pragma unroll
      for (int ct = 0; ct < 4; ct++) {
        float4 bb = *(const float4*)&sbias[ct * 16 + q * 4];
#pragma unroll
        for (int tt = 0; tt < 2; tt++) {
          ST[tt][ct][0] += bb.x;
          ST[tt][ct][1] += bb.y;
          ST[tt][ct][2] += bb.z;
          ST[tt][ct][3] += bb.w;
        }
      }
    }
    // exp2 -> pack -> DIRECT K=16 PV MFMA (A-frag == S^T C/D layout)
#pragma unroll
    for (int ct = 0; ct < 4; ct++) {
      s4 pa[2];
#pragma unroll
      for (int tt = 0; tt < 2; tt++) {
        unsigned u0 =
            __builtin_bit_cast(unsigned, __builtin_amdgcn_exp2f(ST[tt][ct][0]));
        unsigned u1 =
            __builtin_bit_cast(unsigned, __builtin_amdgcn_exp2f(ST[tt][ct][1]));
        unsigned u2 =
            __builtin_bit_cast(unsigned, __builtin_amdgcn_exp2f(ST[tt][ct][2]));
        unsigned u3 =
            __builtin_bit_cast(unsigned, __builtin_amdgcn_exp2f(ST[tt][ct][3]));
        // truncated bf16 used for BOTH numerator (P@V) and denominator
        lsum[tt] += __builtin_bit_cast(float, u0 & 0xffff0000u) +
                    __builtin_bit_cast(float, u1 & 0xffff0000u) +
                    __builtin_bit_cast(float, u2 & 0xffff0000u) +
                    __builtin_bit_cast(float, u3 & 0xffff0000u);
        uint2 pk;
        pk.x = (u0 >> 16) | (u1 & 0xffff0000u);
        pk.y = (u2 >> 16) | (u3 & 0xffff0000u);
        pa[tt] = __builtin_bit_cast(s4, pk);
      }
#pragma unroll
      for (int dt = 0; dt < 4; dt++) {
        s4 vb = *(const s4*)&sVt[dt * 16 + ln][ct * 16 + q * 4];
        O[0][dt] = mfma16b(pa[0], vb, O[0][dt]);
        O[1][dt] = mfma16b(pa[1], vb, O[1][dt]);
      }
    }
  }

  // epilogue: reduce lsum across quads; write O as (B,T,H*DK)
#pragma unroll
  for (int tt = 0; tt < 2; tt++) {
    float s = lsum[tt];
    s += __shfl_xor(s, 16);
    s += __shfl_xor(s, 32);
#pragma unroll
    for (int r = 0; r < 4; r++) {
      float dr = __shfl(s, q * 4 + r);  // lane q*4+r holds denom for that row
      float inv = (dr > 0.f) ? 1.f / dr : 0.f;
      int t = t0 + wv * 32 + tt * 16 + q * 4 + r;
      size_t base = (((size_t)b * NT + t) * NH + (bh & 7)) * NDK;
#pragma unroll
      for (int dt = 0; dt < 4; dt++)
        Oa[base + dt * 16 + ln] = (bf16)(O[tt][dt][r] * inv);
    }
  }
}

// ---------------------------------------------------------------------------
// Output GEMM: 128x64 tiles, bf16 A and W (pre-converted), fp32 out
// ---------------------------------------------------------------------------
__global__ __launch_bounds__(256) void out_gemm(const bf16* __restrict__ A,
                                                const bf16* __restrict__ W,
                                                const float* __restrict__ bias,
                                                float* __restrict__ out) {
  __shared__ bf16 sA[128][72];
  __shared__ bf16 sB[64][72];

  const int tid = threadIdx.x;
  const int l = tid & 63, w = tid >> 6;
  const int q = l >> 4, ln = l & 15;
  const int wm = (w >> 1) * 64, wn = (w & 1) * 32;
  const int bm = blockIdx.x * 128, bn = blockIdx.y * 64;

  f32x4 acc[4][2];
#pragma unroll
  for (int i = 0; i < 4; i++)
#pragma unroll
    for (int j = 0; j < 2; j++) acc[i][j] = (f32x4){0.f, 0.f, 0.f, 0.f};

  const int srow = tid >> 3, scol = (tid & 7) * 8;
  const size_t abase = (size_t)(bm + srow) * 512 + scol;
  const size_t bbase = (size_t)(bn + srow) * 512 + scol;

  bf16x8 ar[4], br[2];
#pragma unroll
  for (int i = 0; i < 4; i++)
    ar[i] = *(const bf16x8*)(A + abase + (size_t)i * 32 * 512);
#pragma unroll
  for (int i = 0; i < 2; i++)
    br[i] = *(const bf16x8*)(W + bbase + (size_t)i * 32 * 512);

  for (int k0 = 0; k0 < 512; k0 += 64) {
    __syncthreads();
#pragma unroll
    for (int i = 0; i < 4; i++) *(bf16x8*)&sA[srow + i * 32][scol] = ar[i];
#pragma unroll
    for (int i = 0; i < 2; i++) *(bf16x8*)&sB[srow + i * 32][scol] = br[i];
    if (k0 + 64 < 512) {
#pragma unroll
      for (int i = 0; i < 4; i++)
        ar[i] = *(const bf16x8*)(A + abase + k0 + 64 + (size_t)i * 32 * 512);
#pragma unroll
      for (int i = 0; i < 2; i++)
        br[i] = *(const bf16x8*)(W + bbase + k0 + 64 + (size_t)i * 32 * 512);
    }
    __syncthreads();
#pragma unroll
    for (int kc = 0; kc < 2; kc++) {
      bf16x8 af[4], bfr[2];
#pragma unroll
      for (int rt = 0; rt < 4; rt++)
        af[rt] = *(const bf16x8*)&sA[wm + rt * 16 + ln][kc * 32 + q * 8];
#pragma unroll
      for (int ct = 0; ct < 2; ct++)
        bfr[ct] = *(const bf16x8*)&sB[wn + ct * 16 + ln][kc * 32 + q * 8];
#pragma unroll
      for (int rt = 0; rt < 4; rt++)
#pragma unroll
        for (int ct = 0; ct < 2; ct++)
          acc[rt][ct] = __builtin_amdgcn_mfma_f32_16x16x32_bf16(
              af[rt], bfr[ct], acc[rt][ct], 0, 0, 0);
    }
  }

#pragma unroll
  for (int rt = 0; rt < 4; rt++)
#pragma unroll
    for (int ct = 0; ct < 2; ct++) {
      const int n = bn + wn + ct * 16 + ln;
      const float bias_n = bias[n];
#pragma unroll
      for (int r = 0; r < 4; r++) {
        const int m = bm + wm + rt * 16 + q * 4 + r;
        out[(size_t)m * 512 + n] = acc[rt][ct][r] + bias_n;
      }
    }
}

// ---------------------------------------------------------------------------
extern "C" void kernel_launch(void* const* d_in, const int* in_sizes, int n_in,
                              void* d_out, int out_size, void* d_ws,
                              size_t ws_size, hipStream_t stream) {
  const float* query = (const float*)d_in[0];
  const float* key = (const float*)d_in[1];
  const float* value = (const float*)d_in[2];
  const int* mask = (const int*)d_in[3];
  const float* pos = (const float*)d_in[4];
  const float* Wq = (const float*)d_in[5];
  const float* bq = (const float*)d_in[6];
  const float* Wk = (const float*)d_in[7];
  const float* bk = (const float*)d_in[8];
  const float* Wv = (const float*)d_in[9];
  const float* bv = (const float*)d_in[10];
  const float* Wo = (const float*)d_in[11];
  const float* bo = (const float*)d_in[12];
  const float* Wp = (const float*)d_in[13];
  const float* pu = (const float*)d_in[14];
  const float* pv = (const float*)d_in[15];
  float* out = (float*)d_out;

  bf16* ws = (bf16*)d_ws;
  dim3 blk(256);
  convert_bf16<<<dim3(7296), blk, 0, stream>>>(query, key, value, pos, Wq, Wk,
                                               Wv, Wp, Wo, ws);
  proj_fused<<<dim3(832), blk, 0, stream>>>(
      ws + OFF_XQ, ws + OFF_XK, ws + OFF_XV, ws + OFF_XP, ws + OFF_WQ,
      ws + OFF_WK, ws + OFF_WV, ws + OFF_WP, bq, bk, bv, pu, pv, ws + OFF_QU,
      ws + OFF_QV, ws + OFF_KB, ws + OFF_VT, ws + OFF_PB);
  flash<<<dim3(8, 32), dim3(512), 0, stream>>>(ws + OFF_QU, ws + OFF_QV,
                                               ws + OFF_KB, ws + OFF_PB,
                                               ws + OFF_VT, mask, ws + OFF_OA);
  out_gemm<<<dim3(64, 8), blk, 0, stream>>>(ws + OFF_OA, ws + OFF_WO, bo, out);
}

// Round 10
// 213.162 us; speedup vs baseline: 1.1349x; 1.0506x over previous
//
#include <hip/hip_runtime.h>

typedef __bf16 bf16;
typedef __attribute__((ext_vector_type(8))) __bf16 bf16x8;
typedef __attribute__((ext_vector_type(4))) __bf16 bf16x4;
typedef __attribute__((ext_vector_type(4))) float f32x4;
typedef __attribute__((ext_vector_type(4))) short s4;

#define NB 4
#define NT 2048
#define ND 512
#define NH 8
#define NDK 64
#define GAMMA 0.1803368801111204f  // 0.125 * log2(e)
#define LTS 152                    // LT stride (shorts)

// workspace layout (bf16 elements)
#define OFF_WQ 13631488ull
#define OFF_WK 13893632ull
#define OFF_WV 14155776ull
#define OFF_WP 14417920ull
#define OFF_WO 14680064ull
#define OFF_QU 14942208ull
#define OFF_QV 19136512ull
#define OFF_KB 23330816ull
#define OFF_VT 27525120ull
#define OFF_PB 31719424ull
#define OFF_OA 0ull  // region below OFF_WQ is free (X no longer staged)

// K=16 bf16 MFMA: A-frag layout == our S^T C/D layout -> direct feed, no LDS
static __device__ __forceinline__ f32x4 mfma16b(s4 a, s4 b, f32x4 c) {
#if __has_builtin(__builtin_amdgcn_mfma_f32_16x16x16bf16_1k)
  return __builtin_amdgcn_mfma_f32_16x16x16bf16_1k(a, b, c, 0, 0, 0);
#else
  f32x4 d;
  asm("v_mfma_f32_16x16x16_bf16 %0, %1, %2, %3"
      : "=v"(d)
      : "v"(a), "v"(b), "v"(c));
  return d;
#endif
}

// ---------------------------------------------------------------------------
// fp32 -> bf16 pre-convert of the 5 weight matrices only (1.3M elems, ~3us)
// ---------------------------------------------------------------------------
__global__ __launch_bounds__(256) void convert_w(
    const float* __restrict__ wq, const float* __restrict__ wk,
    const float* __restrict__ wv, const float* __restrict__ wp,
    const float* __restrict__ wo, bf16* __restrict__ dst) {
  int bid = blockIdx.x;          // 640 blocks, 128 per matrix
  const int m = bid >> 7, sub = bid & 127;
  const float* src;
  if (m == 0) src = wq;
  else if (m == 1) src = wk;
  else if (m == 2) src = wv;
  else if (m == 3) src = wp;
  else src = wo;
  size_t doff = OFF_WQ + (size_t)m * 262144;
  size_t base = (size_t)sub * 2048 + threadIdx.x * 8;
  float4 x0 = *(const float4*)(src + base);
  float4 x1 = *(const float4*)(src + base + 4);
  bf16x8 o;
  o[0] = (bf16)x0.x; o[1] = (bf16)x0.y; o[2] = (bf16)x0.z; o[3] = (bf16)x0.w;
  o[4] = (bf16)x1.x; o[5] = (bf16)x1.y; o[6] = (bf16)x1.z; o[7] = (bf16)x1.w;
  *(bf16x8*)(dst + doff + base) = o;
}

// ---------------------------------------------------------------------------
// coalesced flush helper: LT is [128][LTS] flat LDS scratch of bf16 values
// ---------------------------------------------------------------------------
__device__ __forceinline__ void flush_tile(const bf16* LT, bf16* dst, int bm,
                                           int bn, int tid, bool isP) {
#pragma unroll
  for (int i = 0; i < 8; i++) {
    int chunk = tid + i * 256;
    int mm = chunk >> 4, c8 = (chunk & 15) * 8;
    bf16x8 vv = *(const bf16x8*)&LT[mm * LTS + c8];
    int n = bn + c8, h = n >> 6, d = n & 63;
    int gm = bm + mm;
    size_t gidx;
    if (isP)
      gidx = ((size_t)h * NT + gm) * NDK + d;
    else
      gidx = ((size_t)((gm >> 11) * NH + h) * NT + (gm & 2047)) * NDK + d;
    *(bf16x8*)(dst + gidx) = vv;
  }
}

// ---------------------------------------------------------------------------
// Fused projections. X inputs are RAW fp32 (converted in-register during
// staging -> one b128 LDS write); W inputs pre-converted bf16.
// mode 0: Qu/Qv (B,H,T,DK) -- Qv derived as Qu + (pv-pu)*GAMMA in the flush.
// mode 1: K   mode 2: V transposed (B,H,DK,T)   mode 3: P (H,T,DK)
// Modes 0/1/3 compute C^T (swapped MFMA) -> b64 epilogue writes.
// ---------------------------------------------------------------------------
__global__ __launch_bounds__(256) void proj_fused(
    const float* __restrict__ Xq, const float* __restrict__ Xk,
    const float* __restrict__ Xv, const float* __restrict__ Xp,
    const bf16* __restrict__ wq, const bf16* __restrict__ wk,
    const bf16* __restrict__ wv, const bf16* __restrict__ wp,
    const float* __restrict__ bq, const float* __restrict__ bk,
    const float* __restrict__ bv, const float* __restrict__ pu,
    const float* __restrict__ pv, bf16* __restrict__ Qu, bf16* __restrict__ Qv,
    bf16* __restrict__ Kb, bf16* __restrict__ Vt, bf16* __restrict__ Pb) {
  __shared__ bf16 smem[2][128][76];  // staging; flat [128][152] for epilogue

  const int bid = blockIdx.x;
  const int mode = (bid >= 768) ? 3 : (bid >> 8);
  const int idx = (mode == 3) ? bid - 768 : (bid & 255);
  const int bm = (idx >> 2) * 128, bn = (idx & 3) * 128;

  const float* X;
  const bf16* W;
  if (mode == 0) { X = Xq; W = wq; }
  else if (mode == 1) { X = Xk; W = wk; }
  else if (mode == 2) { X = Xv; W = wv; }
  else { X = Xp; W = wp; }

  const int tid = threadIdx.x;
  const int l = tid & 63, w = tid >> 6;
  const int q = l >> 4, ln = l & 15;
  const int wm = (w >> 1) * 64, wn = (w & 1) * 64;

  f32x4 acc[4][4];
#pragma unroll
  for (int i = 0; i < 4; i++)
#pragma unroll
    for (int j = 0; j < 4; j++) acc[i][j] = (f32x4){0.f, 0.f, 0.f, 0.f};

  const int srow = tid >> 3, scol = (tid & 7) * 8;
  const size_t abase = (size_t)(bm + srow) * 512 + scol;
  const size_t bbase = (size_t)(bn + srow) * 512 + scol;

  float4 arf[4][2];
  bf16x8 br[4];
#pragma unroll
  for (int i = 0; i < 4; i++) {
    arf[i][0] = *(const float4*)(X + abase + (size_t)i * 32 * 512);
    arf[i][1] = *(const float4*)(X + abase + (size_t)i * 32 * 512 + 4);
    br[i] = *(const bf16x8*)(W + bbase + (size_t)i * 32 * 512);
  }

  for (int k0 = 0; k0 < 512; k0 += 64) {
    __syncthreads();
#pragma unroll
    for (int i = 0; i < 4; i++) {
      bf16x8 a8;
      a8[0] = (bf16)arf[i][0].x; a8[1] = (bf16)arf[i][0].y;
      a8[2] = (bf16)arf[i][0].z; a8[3] = (bf16)arf[i][0].w;
      a8[4] = (bf16)arf[i][1].x; a8[5] = (bf16)arf[i][1].y;
      a8[6] = (bf16)arf[i][1].z; a8[7] = (bf16)arf[i][1].w;
      *(bf16x8*)&smem[0][srow + i * 32][scol] = a8;
      *(bf16x8*)&smem[1][srow + i * 32][scol] = br[i];
    }
    if (k0 + 64 < 512) {
#pragma unroll
      for (int i = 0; i < 4; i++) {
        arf[i][0] =
            *(const float4*)(X + abase + k0 + 64 + (size_t)i * 32 * 512);
        arf[i][1] =
            *(const float4*)(X + abase + k0 + 64 + (size_t)i * 32 * 512 + 4);
        br[i] = *(const bf16x8*)(W + bbase + k0 + 64 + (size_t)i * 32 * 512);
      }
    }
    __syncthreads();
#pragma unroll
    for (int kc = 0; kc < 2; kc++) {
      bf16x8 af[4], bfr[4];
#pragma unroll
      for (int rt = 0; rt < 4; rt++)
        af[rt] = *(const bf16x8*)&smem[0][wm + rt * 16 + ln][kc * 32 + q * 8];
#pragma unroll
      for (int ct = 0; ct < 4; ct++)
        bfr[ct] = *(const bf16x8*)&smem[1][wn + ct * 16 + ln][kc * 32 + q * 8];
      if (mode == 2) {
#pragma unroll
        for (int rt = 0; rt < 4; rt++)
#pragma unroll
          for (int ct = 0; ct < 4; ct++)
            acc[rt][ct] = __builtin_amdgcn_mfma_f32_16x16x32_bf16(
                af[rt], bfr[ct], acc[rt][ct], 0, 0, 0);
      } else {  // swapped: acc = C^T tile (rows=n, cols=m)
#pragma unroll
        for (int rt = 0; rt < 4; rt++)
#pragma unroll
          for (int ct = 0; ct < 4; ct++)
            acc[rt][ct] = __builtin_amdgcn_mfma_f32_16x16x32_bf16(
                bfr[ct], af[rt], acc[rt][ct], 0, 0, 0);
      }
    }
  }

  bf16* LT = &smem[0][0][0];  // flat [128][LTS] scratch

  if (mode == 2) {
    __syncthreads();
#pragma unroll
    for (int ct = 0; ct < 4; ct++) {
      const int n = bn + wn + ct * 16 + ln;
      const float bvn = bv[n];
#pragma unroll
      for (int rt = 0; rt < 4; rt++) {
        bf16x4 t4;
#pragma unroll
        for (int r = 0; r < 4; r++) t4[r] = (bf16)(acc[rt][ct][r] + bvn);
        *(bf16x4*)&LT[(wn + ct * 16 + ln) * LTS + wm + rt * 16 + q * 4] = t4;
      }
    }
    __syncthreads();
    const int b = bm >> 11, tb = bm & 2047;
#pragma unroll
    for (int i = 0; i < 8; i++) {
      int chunk = tid + i * 256;
      int nn = chunk >> 4, m8 = (chunk & 15) * 8;
      int n = bn + nn, h = n >> 6, d = n & 63;
      size_t gidx = (((size_t)(b * NH + h)) * NDK + d) * NT + tb + m8;
      *(bf16x8*)(Vt + gidx) = *(const bf16x8*)&LT[nn * LTS + m8];
    }
    return;
  }

  // modes 0/1/3: acc is C^T; lane holds 4 n-consecutive values per tile.
  const int mloc = wm + ln;     // + rt*16
  const int nloc = wn + q * 4;  // + ct*16

  if (mode == 0) {
    float4 addu4[4];
#pragma unroll
    for (int ct = 0; ct < 4; ct++) {
      int n0 = bn + nloc + ct * 16;
      float4 bb = *(const float4*)(bq + n0);
      float4 uu = *(const float4*)(pu + n0);
      addu4[ct] =
          make_float4(bb.x + uu.x, bb.y + uu.y, bb.z + uu.z, bb.w + uu.w);
    }
    __syncthreads();
#pragma unroll
    for (int rt = 0; rt < 4; rt++)
#pragma unroll
      for (int ct = 0; ct < 4; ct++) {
        const float* au = &addu4[ct].x;
        bf16x4 t4;
#pragma unroll
        for (int r = 0; r < 4; r++)
          t4[r] = (bf16)((acc[rt][ct][r] + au[r]) * GAMMA);
        *(bf16x4*)&LT[(mloc + rt * 16) * LTS + nloc + ct * 16] = t4;
      }
    __syncthreads();
    // fused dual flush: Qv = Qu + (pv-pu)*GAMMA (n-range fixed per thread)
    const int c8 = (tid & 15) * 8;
    float delta8[8];
    {
      int n0 = bn + c8;
      float4 u0 = *(const float4*)(pu + n0);
      float4 u1 = *(const float4*)(pu + n0 + 4);
      float4 v0 = *(const float4*)(pv + n0);
      float4 v1 = *(const float4*)(pv + n0 + 4);
      delta8[0] = (v0.x - u0.x) * GAMMA; delta8[1] = (v0.y - u0.y) * GAMMA;
      delta8[2] = (v0.z - u0.z) * GAMMA; delta8[3] = (v0.w - u0.w) * GAMMA;
      delta8[4] = (v1.x - u1.x) * GAMMA; delta8[5] = (v1.y - u1.y) * GAMMA;
      delta8[6] = (v1.z - u1.z) * GAMMA; delta8[7] = (v1.w - u1.w) * GAMMA;
    }
    const int n = bn + c8, h = n >> 6, d = n & 63;
#pragma unroll
    for (int i = 0; i < 8; i++) {
      int chunk = tid + i * 256;
      int mm = chunk >> 4;
      bf16x8 qu8 = *(const bf16x8*)&LT[mm * LTS + c8];
      bf16x8 qv8;
#pragma unroll
      for (int j = 0; j < 8; j++)
        qv8[j] = (bf16)((float)qu8[j] + delta8[j]);
      int gm = bm + mm;
      size_t gidx =
          ((size_t)((gm >> 11) * NH + h) * NT + (gm & 2047)) * NDK + d;
      *(bf16x8*)(Qu + gidx) = qu8;
      *(bf16x8*)(Qv + gidx) = qv8;
    }
    return;
  }

  // mode 1 (K) and mode 3 (P)
  {
    float4 bb4[4];
#pragma unroll
    for (int ct = 0; ct < 4; ct++) {
      int n0 = bn + nloc + ct * 16;
      bb4[ct] = (mode == 1) ? *(const float4*)(bk + n0)
                            : make_float4(0.f, 0.f, 0.f, 0.f);
    }
    __syncthreads();
#pragma unroll
    for (int rt = 0; rt < 4; rt++)
#pragma unroll
      for (int ct = 0; ct < 4; ct++) {
        const float* bbp = &bb4[ct].x;
        bf16x4 t4;
#pragma unroll
        for (int r = 0; r < 4; r++) t4[r] = (bf16)(acc[rt][ct][r] + bbp[r]);
        *(bf16x4*)&LT[(mloc + rt * 16) * LTS + nloc + ct * 16] = t4;
      }
    __syncthreads();
    flush_tile(LT, (mode == 1) ? Kb : Pb, bm, bn, tid, mode == 3);
  }
}

// ---------------------------------------------------------------------------
// Flash attention (R9 winner, unchanged): 512 thr = 8 waves x 32 q-rows,
// grid (8 t, 32 bh); PV via K=16 MFMA direct register feed (A-frag == S^T
// C/D layout); no-max softmax in log2 domain.
// ---------------------------------------------------------------------------
__global__ __launch_bounds__(512) void flash(
    const bf16* __restrict__ Qu, const bf16* __restrict__ Qv,
    const bf16* __restrict__ Kb, const bf16* __restrict__ Pb,
    const bf16* __restrict__ Vt, const int* __restrict__ mask,
    bf16* __restrict__ Oa) {
  __shared__ bf16 sK[64][136];  // [s][0:64]=K, [64:128]=P
  __shared__ bf16 sVt[64][72];  // [d][s]
  __shared__ float sbias[64];

  const int tid = threadIdx.x;
  const int l = tid & 63, wv = tid >> 6;  // 8 waves
  const int q = l >> 4, ln = l & 15;
  const int t0 = blockIdx.x * 256;
  const int bh = blockIdx.y;
  const int b = bh >> 3;

  // Q fragments: 2 t-tiles of 16 rows per wave, resident all kernel
  bf16x8 qf[2][4];
#pragma unroll
  for (int tt = 0; tt < 2; tt++) {
    const size_t qrow = (((size_t)bh) * NT + t0 + wv * 32 + tt * 16 + ln) * NDK;
    qf[tt][0] = *(const bf16x8*)(Qu + qrow + q * 8);
    qf[tt][1] = *(const bf16x8*)(Qu + qrow + 32 + q * 8);
    qf[tt][2] = *(const bf16x8*)(Qv + qrow + q * 8);
    qf[tt][3] = *(const bf16x8*)(Qv + qrow + 32 + q * 8);
  }

  int okacc = 1;
  for (int i = tid; i < NT; i += 512) okacc &= (mask[b * NT + i] != 0);
  const int allones = __syncthreads_and(okacc);

  float lsum[2] = {0.f, 0.f};
  f32x4 O[2][4];
#pragma unroll
  for (int tt = 0; tt < 2; tt++)
#pragma unroll
    for (int dt = 0; dt < 4; dt++) O[tt][dt] = (f32x4){0.f, 0.f, 0.f, 0.f};

  const bf16* Krow = Kb + ((size_t)bh) * NT * NDK;
  const bf16* Prow = Pb + ((size_t)(bh & 7)) * NT * NDK;
  const bf16* Vrow = Vt + ((size_t)bh) * NDK * NT;

  // staging geometry (512 threads)
  const int krow = tid >> 4, kcc = tid & 15;        // K|P: rows krow + i*32
  const int vrow = tid >> 3, vcol = (tid & 7) * 8;  // V: 1 chunk/thread
  const bf16* kpsrc = (kcc < 8) ? (Krow + kcc * 8) : (Prow + (kcc - 8) * 8);

  bf16x8 rk[2], rv;
#pragma unroll
  for (int i = 0; i < 2; i++)
    rk[i] = *(const bf16x8*)(kpsrc + (size_t)(krow + i * 32) * NDK);
  rv = *(const bf16x8*)(Vrow + (size_t)vrow * NT + vcol);

  for (int s0 = 0; s0 < NT; s0 += 64) {
    __syncthreads();  // previous tile's reads complete
#pragma unroll
    for (int i = 0; i < 2; i++) *(bf16x8*)&sK[krow + i * 32][kcc * 8] = rk[i];
    *(bf16x8*)&sVt[vrow][vcol] = rv;
    if (s0 + 64 < NT) {
#pragma unroll
      for (int i = 0; i < 2; i++)
        rk[i] =
            *(const bf16x8*)(kpsrc + (size_t)(s0 + 64 + krow + i * 32) * NDK);
      rv = *(const bf16x8*)(Vrow + (size_t)vrow * NT + s0 + 64 + vcol);
    }
    if (!allones && tid < 64)
      sbias[tid] = mask[b * NT + s0 + tid] ? 0.f : -1e30f;
    __syncthreads();  // writes visible

    // S^T tiles: mfma(A=K-frag, B=Q-frag) -> D[s][t], both t-tiles share kf
    f32x4 ST[2][4];
#pragma unroll
    for (int ct = 0; ct < 4; ct++) {
      ST[0][ct] = (f32x4){0.f, 0.f, 0.f, 0.f};
      ST[1][ct] = (f32x4){0.f, 0.f, 0.f, 0.f};
#pragma unroll
      for (int kc = 0; kc < 4; kc++) {
        bf16x8 kf = *(const bf16x8*)&sK[ct * 16 + ln][kc * 32 + q * 8];
        ST[0][ct] = __builtin_amdgcn_mfma_f32_16x16x32_bf16(kf, qf[0][kc],
                                                            ST[0][ct], 0, 0, 0);
        ST[1][ct] = __builtin_amdgcn_mfma_f32_16x16x32_bf16(kf, qf[1][kc],
                                                            ST[1][ct], 0, 0, 0);
      }
    }
    if (!allones) {
#pragma unroll
      for (int ct = 0; ct < 4; ct++) {
        float4 bb = *(const float4*)&sbias[ct * 16 + q * 4];
#pragma unroll
        for (int tt = 0; tt < 2; tt++) {
          ST[tt][ct][0] += bb.x;
          ST[tt][ct][1] += bb.y;
          ST[tt][ct][2] += bb.z;
          ST[tt][ct][3] += bb.w;
        }
      }
    }
    // exp2 -> pack -> DIRECT K=16 PV MFMA (A-frag == S^T C/D layout)
#pragma unroll
    for (int ct = 0; ct < 4; ct++) {
      s4 pa[2];
#pragma unroll
      for (int tt = 0; tt < 2; tt++) {
        unsigned u0 =
            __builtin_bit_cast(unsigned, __builtin_amdgcn_exp2f(ST[tt][ct][0]));
        unsigned u1 =
            __builtin_bit_cast(unsigned, __builtin_amdgcn_exp2f(ST[tt][ct][1]));
        unsigned u2 =
            __builtin_bit_cast(unsigned, __builtin_amdgcn_exp2f(ST[tt][ct][2]));
        unsigned u3 =
            __builtin_bit_cast(unsigned, __builtin_amdgcn_exp2f(ST[tt][ct][3]));
        // truncated bf16 used for BOTH numerator (P@V) and denominator
        lsum[tt] += __builtin_bit_cast(float, u0 & 0xffff0000u) +
                    __builtin_bit_cast(float, u1 & 0xffff0000u) +
                    __builtin_bit_cast(float, u2 & 0xffff0000u) +
                    __builtin_bit_cast(float, u3 & 0xffff0000u);
        uint2 pk;
        pk.x = (u0 >> 16) | (u1 & 0xffff0000u);
        pk.y = (u2 >> 16) | (u3 & 0xffff0000u);
        pa[tt] = __builtin_bit_cast(s4, pk);
      }
#pragma unroll
      for (int dt = 0; dt < 4; dt++) {
        s4 vb = *(const s4*)&sVt[dt * 16 + ln][ct * 16 + q * 4];
        O[0][dt] = mfma16b(pa[0], vb, O[0][dt]);
        O[1][dt] = mfma16b(pa[1], vb, O[1][dt]);
      }
    }
  }

  // epilogue: reduce lsum across quads; write O as (B,T,H*DK)
#pragma unroll
  for (int tt = 0; tt < 2; tt++) {
    float s = lsum[tt];
    s += __shfl_xor(s, 16);
    s += __shfl_xor(s, 32);
#pragma unroll
    for (int r = 0; r < 4; r++) {
      float dr = __shfl(s, q * 4 + r);  // lane q*4+r holds denom for that row
      float inv = (dr > 0.f) ? 1.f / dr : 0.f;
      int t = t0 + wv * 32 + tt * 16 + q * 4 + r;
      size_t base = (((size_t)b * NT + t) * NH + (bh & 7)) * NDK;
#pragma unroll
      for (int dt = 0; dt < 4; dt++)
        Oa[base + dt * 16 + ln] = (bf16)(O[tt][dt][r] * inv);
    }
  }
}

// ---------------------------------------------------------------------------
// Output GEMM: 128x64 tiles, bf16 A and W (pre-converted), fp32 out
// ---------------------------------------------------------------------------
__global__ __launch_bounds__(256) void out_gemm(const bf16* __restrict__ A,
                                                const bf16* __restrict__ W,
                                                const float* __restrict__ bias,
                                                float* __restrict__ out) {
  __shared__ bf16 sA[128][72];
  __shared__ bf16 sB[64][72];

  const int tid = threadIdx.x;
  const int l = tid & 63, w = tid >> 6;
  const int q = l >> 4, ln = l & 15;
  const int wm = (w >> 1) * 64, wn = (w & 1) * 32;
  const int bm = blockIdx.x * 128, bn = blockIdx.y * 64;

  f32x4 acc[4][2];
#pragma unroll
  for (int i = 0; i < 4; i++)
#pragma unroll
    for (int j = 0; j < 2; j++) acc[i][j] = (f32x4){0.f, 0.f, 0.f, 0.f};

  const int srow = tid >> 3, scol = (tid & 7) * 8;
  const size_t abase = (size_t)(bm + srow) * 512 + scol;
  const size_t bbase = (size_t)(bn + srow) * 512 + scol;

  bf16x8 ar[4], br[2];
#pragma unroll
  for (int i = 0; i < 4; i++)
    ar[i] = *(const bf16x8*)(A + abase + (size_t)i * 32 * 512);
#pragma unroll
  for (int i = 0; i < 2; i++)
    br[i] = *(const bf16x8*)(W + bbase + (size_t)i * 32 * 512);

  for (int k0 = 0; k0 < 512; k0 += 64) {
    __syncthreads();
#pragma unroll
    for (int i = 0; i < 4; i++) *(bf16x8*)&sA[srow + i * 32][scol] = ar[i];
#pragma unroll
    for (int i = 0; i < 2; i++) *(bf16x8*)&sB[srow + i * 32][scol] = br[i];
    if (k0 + 64 < 512) {
#pragma unroll
      for (int i = 0; i < 4; i++)
        ar[i] = *(const bf16x8*)(A + abase + k0 + 64 + (size_t)i * 32 * 512);
#pragma unroll
      for (int i = 0; i < 2; i++)
        br[i] = *(const bf16x8*)(W + bbase + k0 + 64 + (size_t)i * 32 * 512);
    }
    __syncthreads();
#pragma unroll
    for (int kc = 0; kc < 2; kc++) {
      bf16x8 af[4], bfr[2];
#pragma unroll
      for (int rt = 0; rt < 4; rt++)
        af[rt] = *(const bf16x8*)&sA[wm + rt * 16 + ln][kc * 32 + q * 8];
#pragma unroll
      for (int ct = 0; ct < 2; ct++)
        bfr[ct] = *(const bf16x8*)&sB[wn + ct * 16 + ln][kc * 32 + q * 8];
#pragma unroll
      for (int rt = 0; rt < 4; rt++)
#pragma unroll
        for (int ct = 0; ct < 2; ct++)
          acc[rt][ct] = __builtin_amdgcn_mfma_f32_16x16x32_bf16(
              af[rt], bfr[ct], acc[rt][ct], 0, 0, 0);
    }
  }

#pragma unroll
  for (int rt = 0; rt < 4; rt++)
#pragma unroll
    for (int ct = 0; ct < 2; ct++) {
      const int n = bn + wn + ct * 16 + ln;
      const float bias_n = bias[n];
#pragma unroll
      for (int r = 0; r < 4; r++) {
        const int m = bm + wm + rt * 16 + q * 4 + r;
        out[(size_t)m * 512 + n] = acc[rt][ct][r] + bias_n;
      }
    }
}

// ---------------------------------------------------------------------------
extern "C" void kernel_launch(void* const* d_in, const int* in_sizes, int n_in,
                              void* d_out, int out_size, void* d_ws,
                              size_t ws_size, hipStream_t stream) {
  const float* query = (const float*)d_in[0];
  const float* key = (const float*)d_in[1];
  const float* value = (const float*)d_in[2];
  const int* mask = (const int*)d_in[3];
  const float* pos = (const float*)d_in[4];
  const float* Wq = (const float*)d_in[5];
  const float* bq = (const float*)d_in[6];
  const float* Wk = (const float*)d_in[7];
  const float* bk = (const float*)d_in[8];
  const float* Wv = (const float*)d_in[9];
  const float* bv = (const float*)d_in[10];
  const float* Wo = (const float*)d_in[11];
  const float* bo = (const float*)d_in[12];
  const float* Wp = (const float*)d_in[13];
  const float* pu = (const float*)d_in[14];
  const float* pv = (const float*)d_in[15];
  float* out = (float*)d_out;

  bf16* ws = (bf16*)d_ws;
  dim3 blk(256);
  convert_w<<<dim3(640), blk, 0, stream>>>(Wq, Wk, Wv, Wp, Wo, ws);
  proj_fused<<<dim3(832), blk, 0, stream>>>(
      query, key, value, pos, ws + OFF_WQ, ws + OFF_WK, ws + OFF_WV,
      ws + OFF_WP, bq, bk, bv, pu, pv, ws + OFF_QU, ws + OFF_QV, ws + OFF_KB,
      ws + OFF_VT, ws + OFF_PB);
  flash<<<dim3(8, 32), dim3(512), 0, stream>>>(ws + OFF_QU, ws + OFF_QV,
                                               ws + OFF_KB, ws + OFF_PB,
                                               ws + OFF_VT, mask, ws + OFF_OA);
  out_gemm<<<dim3(64, 8), blk, 0, stream>>>(ws + OFF_OA, ws + OFF_WO, bo, out);
}